// Round 5
// baseline (322.091 us; speedup 1.0000x reference)
//
#include <hip/hip_runtime.h>

// SelfAttention: x(4,2048,1024) fp32; Linear y = x @ W^T + b for Q,K,V;
// S = QK^T/32; P = softmax(S); O = P V; out = O @ Wo^T + bo.
// R7: structural fusion round (R6 post-mortem: per-CU GEMM rate is within
// ~13% of the guide's measured K=1024 ceiling (m248: 848 TF); the ~80us gap
// is launches + aux traffic). Changes:
//   - V^T computed DIRECTLY as a GEMM: VT[d][s] = sum_k w_v[d,k] x[s,k]
//     (B^T engine, A=w_v M=1024, B=x N=8192, per-ROW bias) -> transpose_v
//     kernel and V's 32MB round-trip eliminated. Grid 32x8=256 = 1 round.
//   - QKV projection -> fused QK GEMM only (N=2048, 512 blocks = 2 rounds).
//   - All casts + bias concat fused into ONE prep kernel. 13 -> 7 launches.
//   - GEMM engine = R5's verified 128x256 3-buf 2-phase (685 TF, 0 bank
//     conflicts), + bias_row flag.
// Grids (all multiples of 256 blocks @ 1 block/CU):
//   QK (8,64)=512, VT (32,8)=256, QK^T (8,16,4)=512, PV (4,16,4)=256,
//   out (4,64)=256.
//
// Workspace layout (136 MB, aliased by lifetime):
//   [0,16)MB    x_bf16 [8192][1024]     -> later O (PV output)
//   [16,20)MB   wqk bf16 [2048][1024]   (wq|wk fused)
//   [20,22)MB   wv bf16 [1024][1024]
//   [22,24)MB   wo bf16
//   [24,56)MB   QK bf16 [8192][2048]    -> later P (softmax output)
//   [56,72)MB   VT bf16 [1024][8192]    (batch b at columns [b*2048,(b+1)*2048))
//   [72,136)MB  S fp32 [4][2048][2048]; bqk (8KB) lives at 72MB before S

typedef __bf16 bf16x8 __attribute__((ext_vector_type(8)));
typedef float f32x4 __attribute__((ext_vector_type(4)));

__device__ __forceinline__ unsigned short f32_to_bf16(float f) {
  unsigned int u = __float_as_uint(f);
  u += 0x7fffu + ((u >> 16) & 1u);   // round-to-nearest-even
  return (unsigned short)(u >> 16);
}

__device__ __forceinline__ ushort4 cvt4(float4 f) {
  ushort4 u;
  u.x = f32_to_bf16(f.x);
  u.y = f32_to_bf16(f.y);
  u.z = f32_to_bf16(f.z);
  u.w = f32_to_bf16(f.w);
  return u;
}

__device__ __forceinline__ void load_lds16(const void* g, void* l) {
  __builtin_amdgcn_global_load_lds(
      (const __attribute__((address_space(1))) void*)g,
      (__attribute__((address_space(3))) void*)l, 16, 0, 0);
}

// ---------------------------------------------------- fused prep kernel
// One launch: x->xb, wq|wk->wqk, wv->wvb, wo->wob, [bq|bk]->bqk (fp32).
__global__ __launch_bounds__(256) void prep(
    const float4* __restrict__ x, const float4* __restrict__ wq,
    const float4* __restrict__ wk, const float4* __restrict__ wv,
    const float4* __restrict__ wo, const float4* __restrict__ bq,
    const float4* __restrict__ bk, ushort4* __restrict__ xb,
    ushort4* __restrict__ wqk, ushort4* __restrict__ wvb,
    ushort4* __restrict__ wob, float4* __restrict__ bqk) {
  const int NX = 2097152;  // x float4s
  const int NW = 262144;   // one 1024x1024 weight in float4s
  int i = blockIdx.x * 256 + threadIdx.x;
  if (i < NX) {
    xb[i] = cvt4(x[i]);
  } else if (i < NX + NW) {
    int j = i - NX;
    wqk[j] = cvt4(wq[j]);
  } else if (i < NX + 2 * NW) {
    int j = i - NX - NW;
    wqk[NW + j] = cvt4(wk[j]);
  } else if (i < NX + 3 * NW) {
    int j = i - NX - 2 * NW;
    wvb[j] = cvt4(wv[j]);
  } else if (i < NX + 4 * NW) {
    int j = i - NX - 3 * NW;
    wob[j] = cvt4(wo[j]);
  } else if (i < NX + 4 * NW + 512) {
    int j = i - NX - 4 * NW;  // [0,512): bqk float4s (bq 256 | bk 256)
    bqk[j] = (j < 256) ? bq[j] : bk[j - 256];
  }
}

// ------------------------------------------- gemm (B^T form), 128x256 3-buf
// C[b][M][N] = alpha * A[b][M][K] * B[b][N][K]^T + bias
//   bias_row==0: bias[col] (per-N);  bias_row==1: bias[row] (per-M).
// A row stride lda, B row stride ldb. Requires M%128==0, N%256==0, K%64==0,
// K>=128. R5-verified schedule: 2 phases/K-tile, 3-buf LDS (144KB),
// vmcnt(6) counted waits, chunk^(row&7) swizzle (0 bank conflicts measured).
__global__ __launch_bounds__(512, 2) void gemm_bt128x256(
    const unsigned short* __restrict__ A, const unsigned short* __restrict__ B,
    void* __restrict__ C, const float* __restrict__ bias,
    int M, int N, int K, float alpha, int out_bf16, int bias_row,
    int lda, int ldb, long long sA, long long sB, long long sC) {
  __shared__ unsigned short As[3][128][64];  // 48KB  [buf][row][k]
  __shared__ unsigned short Bs[3][256][64];  // 96KB

  const int bz = blockIdx.z;
  A += (long long)bz * sA;
  B += (long long)bz * sB;

  const int bm = blockIdx.y, bn = blockIdx.x;
  const int tid = threadIdx.x;
  const int lane = tid & 63, wave = tid >> 6;
  const int wr = wave >> 2;             // M 64-row slice (0..1)
  const int wc = wave & 3;              // N 64-col slice (0..3)
  const int l16 = lane & 15, quad = lane >> 4;
  // swizzled 16B-chunk element offsets for the two K-slices (row&7 == l16&7)
  const int pc0 = (quad ^ (l16 & 7)) * 8;
  const int pc1 = ((4 + quad) ^ (l16 & 7)) * 8;

  // staging map: thread t covers LDS row srow (+64j); physical chunk t&7 ->
  // fetch logical (swizzled) chunk lch from global. DMA dst is linear.
  const int srow = tid >> 3;
  const int lch = (tid & 7) ^ (srow & 7);
  const unsigned short* gA0 = A + (long long)(bm * 128 + srow) * lda + lch * 8;
  const unsigned short* gB0 = B + (long long)(bn * 256 + srow) * ldb + lch * 8;

  f32x4 acc[4][4] = {};
  bf16x8 af[2][2];  // 2 mi rows per phase
  bf16x8 bf[4][2];  // whole K-tile B fragments (loaded at ph0)

  const int NT = K >> 6;  // 64-wide K tiles

#define STG_A(BUF, KT)                                                      \
  do {                                                                      \
    const unsigned short* _s = gA0 + (long long)(KT) * 64;                  \
    char* _d = (char*)&As[BUF][0][0] + wave * 1024;                         \
    load_lds16(_s, _d);                                                     \
    load_lds16(_s + (long long)64 * lda, _d + 8192);                        \
  } while (0)
#define STG_B(BUF, KT, J0, JN)                                              \
  do {                                                                      \
    const unsigned short* _s = gB0 + (long long)(KT) * 64;                  \
    char* _d = (char*)&Bs[BUF][0][0] + wave * 1024;                         \
    _Pragma("unroll") for (int _j = (J0); _j < (JN); ++_j)                  \
        load_lds16(_s + (long long)(_j * 64) * ldb, _d + _j * 8192);        \
  } while (0)

#define DSA(BUF, P)                                                         \
  do {                                                                      \
    _Pragma("unroll") for (int m2 = 0; m2 < 2; ++m2) {                      \
      const unsigned short* _r =                                            \
          &As[BUF][wr * 64 + ((P) * 2 + m2) * 16 + l16][0];                 \
      af[m2][0] = *(const bf16x8*)(_r + pc0);                               \
      af[m2][1] = *(const bf16x8*)(_r + pc1);                               \
    }                                                                       \
  } while (0)

#define DSB(BUF)                                                            \
  do {                                                                      \
    _Pragma("unroll") for (int ni = 0; ni < 4; ++ni) {                      \
      const unsigned short* _r = &Bs[BUF][wc * 64 + ni * 16 + l16][0];      \
      bf[ni][0] = *(const bf16x8*)(_r + pc0);                               \
      bf[ni][1] = *(const bf16x8*)(_r + pc1);                               \
    }                                                                       \
  } while (0)

#define MM(P)                                                               \
  do {                                                                      \
    _Pragma("unroll") for (int m2 = 0; m2 < 2; ++m2)                        \
        _Pragma("unroll") for (int ni = 0; ni < 4; ++ni) {                  \
      f32x4* _a = &acc[(P) * 2 + m2][ni];                                   \
      *_a = __builtin_amdgcn_mfma_f32_16x16x32_bf16(af[m2][0], bf[ni][0],   \
                                                    *_a, 0, 0, 0);          \
      *_a = __builtin_amdgcn_mfma_f32_16x16x32_bf16(af[m2][1], bf[ni][1],   \
                                                    *_a, 0, 0, 0);          \
    }                                                                       \
  } while (0)

#define BAR() __builtin_amdgcn_s_barrier()
#define WLG() asm volatile("s_waitcnt lgkmcnt(0)" ::: "memory")
#define WVM6() asm volatile("s_waitcnt vmcnt(6)" ::: "memory")
#define P1x() __builtin_amdgcn_s_setprio(1)
#define P0x() __builtin_amdgcn_s_setprio(0)

  // prologue: tiles 0 -> buf0, 1 -> buf1 (6 loads/thread each).
  STG_A(0, 0);
  STG_B(0, 0, 0, 4);
  STG_A(1, 1);
  STG_B(1, 1, 0, 4);
  WVM6();
  BAR();

  // Steady state per tile t (buf cur): stage tile t+2 into buf (cur+2)%3.
  // vmcnt(6) at end of tile t retires tile t+1's 6 loads (issued during
  // t-1, >=2 phases earlier); tile t+2's 6 remain in flight.
  int cur = 0;
  for (int t = 0; t < NT; ++t) {
    int b2 = cur + 2;
    if (b2 >= 3) b2 -= 3;
    const int kt = (t + 2 < NT) ? t + 2 : NT - 1;  // clamped tail restage
    // ph0
    DSB(cur);
    DSA(cur, 0);
    STG_A(b2, kt);
    STG_B(b2, kt, 0, 1);
    BAR();
    WLG();
    P1x();
    MM(0);
    P0x();
    BAR();
    // ph1
    DSA(cur, 1);
    STG_B(b2, kt, 1, 4);
    BAR();
    WLG();
    P1x();
    MM(1);
    P0x();
    WVM6();
    BAR();
    ++cur;
    if (cur == 3) cur = 0;
  }
  asm volatile("s_waitcnt vmcnt(0)" ::: "memory");

  // epilogue: D row = quad*4+r, col = l16 within each 16x16 tile
  const long long orow0 = (long long)bm * 128 + wr * 64 + quad * 4;
  const int ocol0 = bn * 256 + wc * 64 + l16;
  if (out_bf16) {
    unsigned short* Cp = (unsigned short*)C + (long long)bz * sC;
#pragma unroll
    for (int mi = 0; mi < 4; ++mi)
#pragma unroll
      for (int ni = 0; ni < 4; ++ni) {
        const int col = ocol0 + ni * 16;
        const float bcol = (bias && !bias_row) ? bias[col] : 0.f;
#pragma unroll
        for (int r = 0; r < 4; ++r) {
          const float bv =
              (bias && bias_row) ? bias[orow0 + mi * 16 + r] : bcol;
          const float o = acc[mi][ni][r] * alpha + bv;
          Cp[(orow0 + mi * 16 + r) * N + col] = f32_to_bf16(o);
        }
      }
  } else {
    float* Cp = (float*)C + (long long)bz * sC;
#pragma unroll
    for (int mi = 0; mi < 4; ++mi)
#pragma unroll
      for (int ni = 0; ni < 4; ++ni) {
        const int col = ocol0 + ni * 16;
        const float bcol = (bias && !bias_row) ? bias[col] : 0.f;
#pragma unroll
        for (int r = 0; r < 4; ++r) {
          const float bv =
              (bias && bias_row) ? bias[orow0 + mi * 16 + r] : bcol;
          const float o = acc[mi][ni][r] * alpha + bv;
          Cp[(orow0 + mi * 16 + r) * N + col] = o;
        }
      }
  }
#undef STG_A
#undef STG_B
#undef DSA
#undef DSB
#undef MM
#undef BAR
#undef WLG
#undef WVM6
#undef P1x
#undef P0x
}

// ------------------------------------------------------------- row softmax
// S: [8192][2048] fp32 -> P: [8192][2048] bf16. One block per row.
__global__ __launch_bounds__(256) void softmax_rows(
    const float* __restrict__ S, unsigned short* __restrict__ P) {
  const long long row = blockIdx.x;
  const float* s = S + row * 2048;
  const int t = threadIdx.x;
  float v[8];
  float mx = -3.4e38f;
#pragma unroll
  for (int i = 0; i < 8; i++) {
    v[i] = s[t + i * 256];
    mx = fmaxf(mx, v[i]);
  }
#pragma unroll
  for (int o = 32; o >= 1; o >>= 1) mx = fmaxf(mx, __shfl_xor(mx, o));
  __shared__ float red[4], red2[4];
  if ((t & 63) == 0) red[t >> 6] = mx;
  __syncthreads();
  mx = fmaxf(fmaxf(red[0], red[1]), fmaxf(red[2], red[3]));
  float sum = 0.f;
#pragma unroll
  for (int i = 0; i < 8; i++) {
    v[i] = __expf(v[i] - mx);
    sum += v[i];
  }
#pragma unroll
  for (int o = 32; o >= 1; o >>= 1) sum += __shfl_xor(sum, o);
  if ((t & 63) == 0) red2[t >> 6] = sum;
  __syncthreads();
  sum = red2[0] + red2[1] + red2[2] + red2[3];
  const float inv = 1.0f / sum;
  unsigned short* p = P + row * 2048;
#pragma unroll
  for (int i = 0; i < 8; i++) p[t + i * 256] = f32_to_bf16(v[i] * inv);
}

// ----------------------------------------------------------------- launcher
extern "C" void kernel_launch(void* const* d_in, const int* in_sizes, int n_in,
                              void* d_out, int out_size, void* d_ws,
                              size_t ws_size, hipStream_t stream) {
  const float* x = (const float*)d_in[0];
  const float* wq = (const float*)d_in[1];
  const float* bq = (const float*)d_in[2];
  const float* wk = (const float*)d_in[3];
  const float* bk = (const float*)d_in[4];
  const float* wv = (const float*)d_in[5];
  const float* bv = (const float*)d_in[6];
  const float* wo = (const float*)d_in[7];
  const float* bo = (const float*)d_in[8];
  float* out = (float*)d_out;
  char* ws = (char*)d_ws;
  const size_t MB = 1ull << 20;

  unsigned short* xb  = (unsigned short*)(ws + 0);        // 16MB, later O
  unsigned short* wqk = (unsigned short*)(ws + 16 * MB);  // 4MB [2048][1024]
  unsigned short* wvb = (unsigned short*)(ws + 20 * MB);  // 2MB
  unsigned short* wob = (unsigned short*)(ws + 22 * MB);  // 2MB
  unsigned short* QKm = (unsigned short*)(ws + 24 * MB);  // 32MB [8192][2048]
  unsigned short* VT  = (unsigned short*)(ws + 56 * MB);  // 16MB [1024][8192]
  float*          S   = (float*)(ws + 72 * MB);           // 64MB
  float*          bqk = (float*)(ws + 72 * MB);           // 8KB, dies at S
  unsigned short* P   = QKm;                              // 32MB over QK
  unsigned short* O   = xb;                               // 16MB over x_bf16

  // 1) fused prep: all casts + bias concat (one launch)
  //    total float4 work = 2097152 + 4*262144 + 512 = 3146240
  prep<<<dim3(12290), dim3(256), 0, stream>>>(
      (const float4*)x, (const float4*)wq, (const float4*)wk,
      (const float4*)wv, (const float4*)wo, (const float4*)bq,
      (const float4*)bk, (ushort4*)xb, (ushort4*)wqk, (ushort4*)wvb,
      (ushort4*)wob, (float4*)bqk);

  // 2) fused QK projection: [8192,2048] = x_bf16 @ [wq;wk]^T + bqk
  //    grid 8x64 = 512 blocks = 2 full rounds
  gemm_bt128x256<<<dim3(8, 64, 1), dim3(512), 0, stream>>>(
      xb, wqk, QKm, bqk, 8192, 2048, 1024, 1.f, 1, 0, 1024, 1024, 0, 0, 0);

  // 3) VT[d][s] = sum_k w_v[d,k] x[s,k] + bv[d]  (per-ROW bias)
  //    grid 32x8 = 256 blocks = 1 full round; replaces V-gemm + transpose
  gemm_bt128x256<<<dim3(32, 8, 1), dim3(512), 0, stream>>>(
      wvb, xb, VT, bv, 1024, 8192, 1024, 1.f, 1, 1, 1024, 1024, 0, 0, 0);

  // 4) S = Q K^T / 32, fp32, batched over 4 (Q,K are column slices of QKm)
  //    grid 8x16x4 = 512 blocks = 2 full rounds
  gemm_bt128x256<<<dim3(8, 16, 4), dim3(512), 0, stream>>>(
      QKm, QKm + 1024, S, nullptr, 2048, 2048, 1024, 0.03125f, 0, 0, 2048,
      2048, 2048ll * 2048, 2048ll * 2048, 2048ll * 2048);

  // 5) P = softmax rows of S (bf16), over dead QK region
  softmax_rows<<<dim3(8192), dim3(256), 0, stream>>>(S, P);

  // 6) O = P @ V: B = VT (batch b at column offset b*2048, ldb=8192)
  //    grid 4x16x4 = 256 blocks = 1 full round
  gemm_bt128x256<<<dim3(4, 16, 4), dim3(512), 0, stream>>>(
      P, VT, O, nullptr, 2048, 1024, 2048, 1.f, 1, 0, 2048, 8192,
      2048ll * 2048, 2048ll, 2048ll * 1024);

  // 7) out = O @ Wo^T + bo, fp32 — grid 4x64 = 256 = 1 full round
  gemm_bt128x256<<<dim3(4, 64, 1), dim3(512), 0, stream>>>(
      O, wob, out, bo, 8192, 1024, 1024, 1.f, 0, 0, 1024, 1024, 0, 0, 0);
}

// Round 6
// 317.256 us; speedup vs baseline: 1.0152x; 1.0152x over previous
//
#include <hip/hip_runtime.h>

// SelfAttention: x(4,2048,1024) fp32; Linear y = x @ W^T + b for Q,K,V;
// S = QK^T/32; P = softmax(S); O = P V; out = O @ Wo^T + bo.
// R8 = R7 + T1 XCD-aware bijective block swizzle in the GEMM engine.
//   R7 post-mortem: QK proj fetched 69.7MB vs 20MB ideal (3.5x over-fetch),
//   564-750 TF resident across shapes, MfmaUtil ~22%, conflicts 0 ->
//   cross-XCD L2 duplication (consecutive ids sharing A-panels round-robin
//   to different XCDs). Fix: logical = (hw%8)*(nwg/8) + hw/8 so each XCD's
//   blocks form a contiguous logical range (panels become L2-resident).
//   All grids are multiples of 8 blocks (512/256/512/256/256).
// Structure unchanged from R7:
//   - VT computed directly as GEMM (A=w_v, B=x, per-row bias): no transpose.
//   - fused QK projection; one prep kernel (casts + bias concat); 7 launches.
//   - GEMM engine: 128x256, 3-buf LDS (144KB), 2 phases/K-tile, vmcnt(6)
//     counted waits, chunk^(row&7) swizzle (0 bank conflicts measured).
//
// Workspace layout (136 MB, aliased by lifetime):
//   [0,16)MB    x_bf16 [8192][1024]     -> later O (PV output)
//   [16,20)MB   wqk bf16 [2048][1024]   (wq|wk fused)
//   [20,22)MB   wv bf16 [1024][1024]
//   [22,24)MB   wo bf16
//   [24,56)MB   QK bf16 [8192][2048]    -> later P (softmax output)
//   [56,72)MB   VT bf16 [1024][8192]    (batch b at columns [b*2048,(b+1)*2048))
//   [72,136)MB  S fp32 [4][2048][2048]; bqk (8KB) lives at 72MB before S

typedef __bf16 bf16x8 __attribute__((ext_vector_type(8)));
typedef float f32x4 __attribute__((ext_vector_type(4)));

__device__ __forceinline__ unsigned short f32_to_bf16(float f) {
  unsigned int u = __float_as_uint(f);
  u += 0x7fffu + ((u >> 16) & 1u);   // round-to-nearest-even
  return (unsigned short)(u >> 16);
}

__device__ __forceinline__ ushort4 cvt4(float4 f) {
  ushort4 u;
  u.x = f32_to_bf16(f.x);
  u.y = f32_to_bf16(f.y);
  u.z = f32_to_bf16(f.z);
  u.w = f32_to_bf16(f.w);
  return u;
}

__device__ __forceinline__ void load_lds16(const void* g, void* l) {
  __builtin_amdgcn_global_load_lds(
      (const __attribute__((address_space(1))) void*)g,
      (__attribute__((address_space(3))) void*)l, 16, 0, 0);
}

// ---------------------------------------------------- fused prep kernel
// One launch: x->xb, wq|wk->wqk, wv->wvb, wo->wob, [bq|bk]->bqk (fp32).
__global__ __launch_bounds__(256) void prep(
    const float4* __restrict__ x, const float4* __restrict__ wq,
    const float4* __restrict__ wk, const float4* __restrict__ wv,
    const float4* __restrict__ wo, const float4* __restrict__ bq,
    const float4* __restrict__ bk, ushort4* __restrict__ xb,
    ushort4* __restrict__ wqk, ushort4* __restrict__ wvb,
    ushort4* __restrict__ wob, float4* __restrict__ bqk) {
  const int NX = 2097152;  // x float4s
  const int NW = 262144;   // one 1024x1024 weight in float4s
  int i = blockIdx.x * 256 + threadIdx.x;
  if (i < NX) {
    xb[i] = cvt4(x[i]);
  } else if (i < NX + NW) {
    int j = i - NX;
    wqk[j] = cvt4(wq[j]);
  } else if (i < NX + 2 * NW) {
    int j = i - NX - NW;
    wqk[NW + j] = cvt4(wk[j]);
  } else if (i < NX + 3 * NW) {
    int j = i - NX - 2 * NW;
    wvb[j] = cvt4(wv[j]);
  } else if (i < NX + 4 * NW) {
    int j = i - NX - 3 * NW;
    wob[j] = cvt4(wo[j]);
  } else if (i < NX + 4 * NW + 512) {
    int j = i - NX - 4 * NW;  // [0,512): bqk float4s (bq 256 | bk 256)
    bqk[j] = (j < 256) ? bq[j] : bk[j - 256];
  }
}

// ------------------------------------------- gemm (B^T form), 128x256 3-buf
// C[b][M][N] = alpha * A[b][M][K] * B[b][N][K]^T + bias
//   bias_row==0: bias[col] (per-N);  bias_row==1: bias[row] (per-M).
// A row stride lda, B row stride ldb. Requires M%128==0, N%256==0, K%64==0,
// K>=128, total blocks % 8 == 0 (for the XCD swizzle bijection).
__global__ __launch_bounds__(512, 2) void gemm_bt128x256(
    const unsigned short* __restrict__ A, const unsigned short* __restrict__ B,
    void* __restrict__ C, const float* __restrict__ bias,
    int M, int N, int K, float alpha, int out_bf16, int bias_row,
    int lda, int ldb, long long sA, long long sB, long long sC) {
  __shared__ unsigned short As[3][128][64];  // 48KB  [buf][row][k]
  __shared__ unsigned short Bs[3][256][64];  // 96KB

  // T1 XCD swizzle: hw block id -> logical tile id. XCD j hosts hw ids
  // {j, j+8, ...}; logical = (hw%8)*(nwg/8)+hw/8 makes XCD j's logical ids
  // the contiguous range [j*q,(j+1)*q) -> shared A/B panels stay in its L2.
  {
    const int hw =
        blockIdx.x + gridDim.x * (blockIdx.y + gridDim.y * blockIdx.z);
    const int nwg = gridDim.x * gridDim.y * gridDim.z;
    const int q = nwg >> 3;
    const int lg = (hw & 7) * q + (hw >> 3);
    // decompose (x fastest, then y, then z)
    // (reuse names below via locals)
    const int bx = lg % gridDim.x;
    const int rem = lg / gridDim.x;
    const int by = rem % gridDim.y;
    const int bz_ = rem / gridDim.y;
    // stash in shared-free registers
    // (fall through: use bx/by/bz_)
    const int bz = bz_;
    A += (long long)bz * sA;
    B += (long long)bz * sB;

    const int bm = by, bn = bx;
    const int tid = threadIdx.x;
    const int lane = tid & 63, wave = tid >> 6;
    const int wr = wave >> 2;             // M 64-row slice (0..1)
    const int wc = wave & 3;              // N 64-col slice (0..3)
    const int l16 = lane & 15, quad = lane >> 4;
    // swizzled 16B-chunk element offsets for the two K-slices (row&7==l16&7)
    const int pc0 = (quad ^ (l16 & 7)) * 8;
    const int pc1 = ((4 + quad) ^ (l16 & 7)) * 8;

    // staging map: thread t covers LDS row srow (+64j); physical chunk t&7 ->
    // fetch logical (swizzled) chunk lch from global. DMA dst is linear.
    const int srow = tid >> 3;
    const int lch = (tid & 7) ^ (srow & 7);
    const unsigned short* gA0 =
        A + (long long)(bm * 128 + srow) * lda + lch * 8;
    const unsigned short* gB0 =
        B + (long long)(bn * 256 + srow) * ldb + lch * 8;

    f32x4 acc[4][4] = {};
    bf16x8 af[2][2];  // 2 mi rows per phase
    bf16x8 bf[4][2];  // whole K-tile B fragments (loaded at ph0)

    const int NT = K >> 6;  // 64-wide K tiles

#define STG_A(BUF, KT)                                                      \
  do {                                                                      \
    const unsigned short* _s = gA0 + (long long)(KT) * 64;                  \
    char* _d = (char*)&As[BUF][0][0] + wave * 1024;                         \
    load_lds16(_s, _d);                                                     \
    load_lds16(_s + (long long)64 * lda, _d + 8192);                        \
  } while (0)
#define STG_B(BUF, KT, J0, JN)                                              \
  do {                                                                      \
    const unsigned short* _s = gB0 + (long long)(KT) * 64;                  \
    char* _d = (char*)&Bs[BUF][0][0] + wave * 1024;                         \
    _Pragma("unroll") for (int _j = (J0); _j < (JN); ++_j)                  \
        load_lds16(_s + (long long)(_j * 64) * ldb, _d + _j * 8192);        \
  } while (0)

#define DSA(BUF, P)                                                         \
  do {                                                                      \
    _Pragma("unroll") for (int m2 = 0; m2 < 2; ++m2) {                      \
      const unsigned short* _r =                                            \
          &As[BUF][wr * 64 + ((P) * 2 + m2) * 16 + l16][0];                 \
      af[m2][0] = *(const bf16x8*)(_r + pc0);                               \
      af[m2][1] = *(const bf16x8*)(_r + pc1);                               \
    }                                                                       \
  } while (0)

#define DSB(BUF)                                                            \
  do {                                                                      \
    _Pragma("unroll") for (int ni = 0; ni < 4; ++ni) {                      \
      const unsigned short* _r = &Bs[BUF][wc * 64 + ni * 16 + l16][0];      \
      bf[ni][0] = *(const bf16x8*)(_r + pc0);                               \
      bf[ni][1] = *(const bf16x8*)(_r + pc1);                               \
    }                                                                       \
  } while (0)

#define MM(P)                                                               \
  do {                                                                      \
    _Pragma("unroll") for (int m2 = 0; m2 < 2; ++m2)                        \
        _Pragma("unroll") for (int ni = 0; ni < 4; ++ni) {                  \
      f32x4* _a = &acc[(P) * 2 + m2][ni];                                   \
      *_a = __builtin_amdgcn_mfma_f32_16x16x32_bf16(af[m2][0], bf[ni][0],   \
                                                    *_a, 0, 0, 0);          \
      *_a = __builtin_amdgcn_mfma_f32_16x16x32_bf16(af[m2][1], bf[ni][1],   \
                                                    *_a, 0, 0, 0);          \
    }                                                                       \
  } while (0)

#define BAR() __builtin_amdgcn_s_barrier()
#define WLG() asm volatile("s_waitcnt lgkmcnt(0)" ::: "memory")
#define WVM6() asm volatile("s_waitcnt vmcnt(6)" ::: "memory")
#define P1x() __builtin_amdgcn_s_setprio(1)
#define P0x() __builtin_amdgcn_s_setprio(0)

    // prologue: tiles 0 -> buf0, 1 -> buf1 (6 loads/thread each).
    STG_A(0, 0);
    STG_B(0, 0, 0, 4);
    STG_A(1, 1);
    STG_B(1, 1, 0, 4);
    WVM6();
    BAR();

    // Steady state per tile t (buf cur): stage tile t+2 into buf (cur+2)%3.
    // vmcnt(6) at end of tile t retires tile t+1's 6 loads (issued during
    // t-1, >=2 phases earlier); tile t+2's 6 remain in flight.
    int cur = 0;
    for (int t = 0; t < NT; ++t) {
      int b2 = cur + 2;
      if (b2 >= 3) b2 -= 3;
      const int kt = (t + 2 < NT) ? t + 2 : NT - 1;  // clamped tail restage
      // ph0
      DSB(cur);
      DSA(cur, 0);
      STG_A(b2, kt);
      STG_B(b2, kt, 0, 1);
      BAR();
      WLG();
      P1x();
      MM(0);
      P0x();
      BAR();
      // ph1
      DSA(cur, 1);
      STG_B(b2, kt, 1, 4);
      BAR();
      WLG();
      P1x();
      MM(1);
      P0x();
      WVM6();
      BAR();
      ++cur;
      if (cur == 3) cur = 0;
    }
    asm volatile("s_waitcnt vmcnt(0)" ::: "memory");

    // epilogue: D row = quad*4+r, col = l16 within each 16x16 tile
    const long long orow0 = (long long)bm * 128 + wr * 64 + quad * 4;
    const int ocol0 = bn * 256 + wc * 64 + l16;
    if (out_bf16) {
      unsigned short* Cp = (unsigned short*)C + (long long)bz * sC;
#pragma unroll
      for (int mi = 0; mi < 4; ++mi)
#pragma unroll
        for (int ni = 0; ni < 4; ++ni) {
          const int col = ocol0 + ni * 16;
          const float bcol = (bias && !bias_row) ? bias[col] : 0.f;
#pragma unroll
          for (int r = 0; r < 4; ++r) {
            const float bv =
                (bias && bias_row) ? bias[orow0 + mi * 16 + r] : bcol;
            const float o = acc[mi][ni][r] * alpha + bv;
            Cp[(orow0 + mi * 16 + r) * N + col] = f32_to_bf16(o);
          }
        }
    } else {
      float* Cp = (float*)C + (long long)bz * sC;
#pragma unroll
      for (int mi = 0; mi < 4; ++mi)
#pragma unroll
        for (int ni = 0; ni < 4; ++ni) {
          const int col = ocol0 + ni * 16;
          const float bcol = (bias && !bias_row) ? bias[col] : 0.f;
#pragma unroll
          for (int r = 0; r < 4; ++r) {
            const float bv =
                (bias && bias_row) ? bias[orow0 + mi * 16 + r] : bcol;
            const float o = acc[mi][ni][r] * alpha + bv;
            Cp[(orow0 + mi * 16 + r) * N + col] = o;
          }
        }
    }
  }
#undef STG_A
#undef STG_B
#undef DSA
#undef DSB
#undef MM
#undef BAR
#undef WLG
#undef WVM6
#undef P1x
#undef P0x
}

// ------------------------------------------------------------- row softmax
// S: [8192][2048] fp32 -> P: [8192][2048] bf16. One block per row.
__global__ __launch_bounds__(256) void softmax_rows(
    const float* __restrict__ S, unsigned short* __restrict__ P) {
  const long long row = blockIdx.x;
  const float* s = S + row * 2048;
  const int t = threadIdx.x;
  float v[8];
  float mx = -3.4e38f;
#pragma unroll
  for (int i = 0; i < 8; i++) {
    v[i] = s[t + i * 256];
    mx = fmaxf(mx, v[i]);
  }
#pragma unroll
  for (int o = 32; o >= 1; o >>= 1) mx = fmaxf(mx, __shfl_xor(mx, o));
  __shared__ float red[4], red2[4];
  if ((t & 63) == 0) red[t >> 6] = mx;
  __syncthreads();
  mx = fmaxf(fmaxf(red[0], red[1]), fmaxf(red[2], red[3]));
  float sum = 0.f;
#pragma unroll
  for (int i = 0; i < 8; i++) {
    v[i] = __expf(v[i] - mx);
    sum += v[i];
  }
#pragma unroll
  for (int o = 32; o >= 1; o >>= 1) sum += __shfl_xor(sum, o);
  if ((t & 63) == 0) red2[t >> 6] = sum;
  __syncthreads();
  sum = red2[0] + red2[1] + red2[2] + red2[3];
  const float inv = 1.0f / sum;
  unsigned short* p = P + row * 2048;
#pragma unroll
  for (int i = 0; i < 8; i++) p[t + i * 256] = f32_to_bf16(v[i] * inv);
}

// ----------------------------------------------------------------- launcher
extern "C" void kernel_launch(void* const* d_in, const int* in_sizes, int n_in,
                              void* d_out, int out_size, void* d_ws,
                              size_t ws_size, hipStream_t stream) {
  const float* x = (const float*)d_in[0];
  const float* wq = (const float*)d_in[1];
  const float* bq = (const float*)d_in[2];
  const float* wk = (const float*)d_in[3];
  const float* bk = (const float*)d_in[4];
  const float* wv = (const float*)d_in[5];
  const float* bv = (const float*)d_in[6];
  const float* wo = (const float*)d_in[7];
  const float* bo = (const float*)d_in[8];
  float* out = (float*)d_out;
  char* ws = (char*)d_ws;
  const size_t MB = 1ull << 20;

  unsigned short* xb  = (unsigned short*)(ws + 0);        // 16MB, later O
  unsigned short* wqk = (unsigned short*)(ws + 16 * MB);  // 4MB [2048][1024]
  unsigned short* wvb = (unsigned short*)(ws + 20 * MB);  // 2MB
  unsigned short* wob = (unsigned short*)(ws + 22 * MB);  // 2MB
  unsigned short* QKm = (unsigned short*)(ws + 24 * MB);  // 32MB [8192][2048]
  unsigned short* VT  = (unsigned short*)(ws + 56 * MB);  // 16MB [1024][8192]
  float*          S   = (float*)(ws + 72 * MB);           // 64MB
  float*          bqk = (float*)(ws + 72 * MB);           // 8KB, dies at S
  unsigned short* P   = QKm;                              // 32MB over QK
  unsigned short* O   = xb;                               // 16MB over x_bf16

  // 1) fused prep: all casts + bias concat (one launch)
  //    total float4 work = 2097152 + 4*262144 + 512 = 3146240
  prep<<<dim3(12290), dim3(256), 0, stream>>>(
      (const float4*)x, (const float4*)wq, (const float4*)wk,
      (const float4*)wv, (const float4*)wo, (const float4*)bq,
      (const float4*)bk, (ushort4*)xb, (ushort4*)wqk, (ushort4*)wvb,
      (ushort4*)wob, (float4*)bqk);

  // 2) fused QK projection: [8192,2048] = x_bf16 @ [wq;wk]^T + bqk
  //    grid 8x64 = 512 blocks = 2 full rounds
  gemm_bt128x256<<<dim3(8, 64, 1), dim3(512), 0, stream>>>(
      xb, wqk, QKm, bqk, 8192, 2048, 1024, 1.f, 1, 0, 1024, 1024, 0, 0, 0);

  // 3) VT[d][s] = sum_k w_v[d,k] x[s,k] + bv[d]  (per-ROW bias)
  //    grid 32x8 = 256 blocks = 1 full round; replaces V-gemm + transpose
  gemm_bt128x256<<<dim3(32, 8, 1), dim3(512), 0, stream>>>(
      wvb, xb, VT, bv, 1024, 8192, 1024, 1.f, 1, 1, 1024, 1024, 0, 0, 0);

  // 4) S = Q K^T / 32, fp32, batched over 4 (Q,K are column slices of QKm)
  //    grid 8x16x4 = 512 blocks = 2 full rounds
  gemm_bt128x256<<<dim3(8, 16, 4), dim3(512), 0, stream>>>(
      QKm, QKm + 1024, S, nullptr, 2048, 2048, 1024, 0.03125f, 0, 0, 2048,
      2048, 2048ll * 2048, 2048ll * 2048, 2048ll * 2048);

  // 5) P = softmax rows of S (bf16), over dead QK region
  softmax_rows<<<dim3(8192), dim3(256), 0, stream>>>(S, P);

  // 6) O = P @ V: B = VT (batch b at column offset b*2048, ldb=8192)
  //    grid 4x16x4 = 256 blocks = 1 full round
  gemm_bt128x256<<<dim3(4, 16, 4), dim3(512), 0, stream>>>(
      P, VT, O, nullptr, 2048, 1024, 2048, 1.f, 1, 0, 2048, 8192,
      2048ll * 2048, 2048ll, 2048ll * 1024);

  // 7) out = O @ Wo^T + bo, fp32 — grid 4x64 = 256 = 1 full round
  gemm_bt128x256<<<dim3(4, 64, 1), dim3(512), 0, stream>>>(
      O, wob, out, bo, 8192, 1024, 1024, 1.f, 0, 0, 1024, 1024, 0, 0, 0);
}

// Round 7
// 297.521 us; speedup vs baseline: 1.0826x; 1.0663x over previous
//
#include <hip/hip_runtime.h>

// SelfAttention: x(4,2048,1024) fp32; Linear y = x @ W^T + b for Q,K,V;
// S = QK^T/32; P = softmax(S); O = P V; out = O @ Wo^T + bo.
// R9: mixed-engine assignment (R8 post-mortem: latency-bound engines; time
// model closes at measured block-rates: 128x256 = 0.067GF/29.5us,
// 256^2dp = 0.134GF/44.7us -> 256dp wins per-GF wherever grid%256==0).
//   - QK proj (8,32)=256 blocks and QK^T (8,8,4)=256 blocks -> gemm_bt256dp
//     (R6-verified deep-pipeline 256^2, + T1 bijective XCD swizzle).
//   - VT (32,8), PV (4,16,4), out (4,64) -> gemm_bt128x256 (R8-verified,
//     grids all 256 blocks; 256dp would halve the machine on these).
// Structure otherwise = R8: VT-as-GEMM (no transpose), fused QK projection,
// one prep kernel, 7 launches, T1 swizzle + chunk^(row&7) LDS involution
// everywhere (0 bank conflicts measured).
//
// Workspace layout (136 MB, aliased by lifetime):
//   [0,16)MB    x_bf16 [8192][1024]     -> later O (PV output)
//   [16,20)MB   wqk bf16 [2048][1024]   (wq|wk fused)
//   [20,22)MB   wv bf16 [1024][1024]
//   [22,24)MB   wo bf16
//   [24,56)MB   QK bf16 [8192][2048]    -> later P (softmax output)
//   [56,72)MB   VT bf16 [1024][8192]    (batch b at cols [b*2048,(b+1)*2048))
//   [72,136)MB  S fp32 [4][2048][2048]; bqk (8KB) lives at 72MB before S

typedef __bf16 bf16x8 __attribute__((ext_vector_type(8)));
typedef float f32x4 __attribute__((ext_vector_type(4)));

__device__ __forceinline__ unsigned short f32_to_bf16(float f) {
  unsigned int u = __float_as_uint(f);
  u += 0x7fffu + ((u >> 16) & 1u);   // round-to-nearest-even
  return (unsigned short)(u >> 16);
}

__device__ __forceinline__ ushort4 cvt4(float4 f) {
  ushort4 u;
  u.x = f32_to_bf16(f.x);
  u.y = f32_to_bf16(f.y);
  u.z = f32_to_bf16(f.z);
  u.w = f32_to_bf16(f.w);
  return u;
}

__device__ __forceinline__ void load_lds16(const void* g, void* l) {
  __builtin_amdgcn_global_load_lds(
      (const __attribute__((address_space(1))) void*)g,
      (__attribute__((address_space(3))) void*)l, 16, 0, 0);
}

// ---------------------------------------------------- fused prep kernel
__global__ __launch_bounds__(256) void prep(
    const float4* __restrict__ x, const float4* __restrict__ wq,
    const float4* __restrict__ wk, const float4* __restrict__ wv,
    const float4* __restrict__ wo, const float4* __restrict__ bq,
    const float4* __restrict__ bk, ushort4* __restrict__ xb,
    ushort4* __restrict__ wqk, ushort4* __restrict__ wvb,
    ushort4* __restrict__ wob, float4* __restrict__ bqk) {
  const int NX = 2097152;  // x float4s
  const int NW = 262144;   // one 1024x1024 weight in float4s
  int i = blockIdx.x * 256 + threadIdx.x;
  if (i < NX) {
    xb[i] = cvt4(x[i]);
  } else if (i < NX + NW) {
    int j = i - NX;
    wqk[j] = cvt4(wq[j]);
  } else if (i < NX + 2 * NW) {
    int j = i - NX - NW;
    wqk[NW + j] = cvt4(wk[j]);
  } else if (i < NX + 3 * NW) {
    int j = i - NX - 2 * NW;
    wvb[j] = cvt4(wv[j]);
  } else if (i < NX + 4 * NW) {
    int j = i - NX - 3 * NW;
    wob[j] = cvt4(wo[j]);
  } else if (i < NX + 4 * NW + 512) {
    int j = i - NX - 4 * NW;  // [0,512): bqk float4s (bq 256 | bk 256)
    bqk[j] = (j < 256) ? bq[j] : bk[j - 256];
  }
}

// --------------------------------- gemm (B^T form), 256^2 deep-pipeline
// C[b][M][N] = alpha * A[b][M][K] * B[b][N][K]^T + bias[N]
// Requires M%256==0, N%256==0, K%128==0, blocks%8==0.
__global__ __launch_bounds__(512, 2) void gemm_bt256dp(
    const unsigned short* __restrict__ A, const unsigned short* __restrict__ B,
    void* __restrict__ C, const float* __restrict__ bias,
    int M, int N, int K, float alpha, int out_bf16, int lda, int ldb,
    long long sA, long long sB, long long sC) {
  __shared__ unsigned short As[3][2][128 * 64];  // 96KB [buf][half][row*64+k]
  __shared__ unsigned short Bs[2][2][128 * 64];  // 64KB  (total 160KB)

  // T1 XCD swizzle: XCD j hosts hw ids {j, j+8, ...}; remap so its logical
  // ids are contiguous -> shared panels stay in its private L2.
  const int hw = blockIdx.x + gridDim.x * (blockIdx.y + gridDim.y * blockIdx.z);
  const int nwg = gridDim.x * gridDim.y * gridDim.z;
  const int lg = (hw & 7) * (nwg >> 3) + (hw >> 3);
  const int bn = lg % gridDim.x;
  const int rem = lg / gridDim.x;
  const int bm = rem % gridDim.y;
  const int bz = rem / gridDim.y;

  A += (long long)bz * sA;
  B += (long long)bz * sB;

  const int tid = threadIdx.x;
  const int lane = tid & 63, wave = tid >> 6;
  const int wr = wave >> 2;             // M half (128 rows)
  const int wc = wave & 3;              // N quarter (64 cols)
  const int l16 = lane & 15, quad = lane >> 4;
  const int wbh = wc >> 1;              // B half this wave reads
  const int wbr = (wc & 1) * 64 + l16;  // B row base within that half
  const int pc0 = (quad ^ (l16 & 7)) * 8;
  const int pc1 = ((4 + quad) ^ (l16 & 7)) * 8;

  const int srow = tid >> 3;
  const int lch = (tid & 7) ^ (srow & 7);
  const unsigned short* gA0 = A + (long long)(bm * 256 + srow) * lda + lch * 8;
  const unsigned short* gB0 = B + (long long)(bn * 256 + srow) * ldb + lch * 8;

  f32x4 acc[8][4] = {};
  bf16x8 af[2][2];  // current mi-pair fragments
  bf16x8 bf[4][2];  // whole-K-step B fragments (read at P1, live P1-P4)

  const int NT = K >> 6;

#define STA(BUF, H, KT)                                                     \
  do {                                                                      \
    const unsigned short* _s =                                              \
        gA0 + (long long)(H) * 128 * lda + (long long)(KT) * 64;            \
    char* _d = (char*)&As[BUF][H][0] + wave * 1024;                         \
    load_lds16(_s, _d);                                                     \
    load_lds16(_s + (long long)64 * lda, _d + 8192);                        \
  } while (0)
#define STB(BUF, H, KT)                                                     \
  do {                                                                      \
    const unsigned short* _s =                                              \
        gB0 + (long long)(H) * 128 * ldb + (long long)(KT) * 64;            \
    char* _d = (char*)&Bs[BUF][H][0] + wave * 1024;                         \
    load_lds16(_s, _d);                                                     \
    load_lds16(_s + (long long)64 * ldb, _d + 8192);                        \
  } while (0)

#define DSAq(BUF, MIP)                                                      \
  do {                                                                      \
    _Pragma("unroll") for (int m2 = 0; m2 < 2; ++m2) {                      \
      const unsigned short* _r =                                            \
          &As[BUF][wr][(((MIP) * 2 + m2) * 16 + l16) * 64];                 \
      af[m2][0] = *(const bf16x8*)(_r + pc0);                               \
      af[m2][1] = *(const bf16x8*)(_r + pc1);                               \
    }                                                                       \
  } while (0)

#define DSBq(BUF)                                                           \
  do {                                                                      \
    _Pragma("unroll") for (int ni = 0; ni < 4; ++ni) {                      \
      const unsigned short* _r = &Bs[BUF][wbh][(wbr + ni * 16) * 64];       \
      bf[ni][0] = *(const bf16x8*)(_r + pc0);                               \
      bf[ni][1] = *(const bf16x8*)(_r + pc1);                               \
    }                                                                       \
  } while (0)

#define MMq(MIP)                                                            \
  do {                                                                      \
    _Pragma("unroll") for (int m2 = 0; m2 < 2; ++m2)                        \
        _Pragma("unroll") for (int ni = 0; ni < 4; ++ni) {                  \
      f32x4* _a = &acc[(MIP) * 2 + m2][ni];                                 \
      *_a = __builtin_amdgcn_mfma_f32_16x16x32_bf16(af[m2][0], bf[ni][0],   \
                                                    *_a, 0, 0, 0);          \
      *_a = __builtin_amdgcn_mfma_f32_16x16x32_bf16(af[m2][1], bf[ni][1],   \
                                                    *_a, 0, 0, 0);          \
    }                                                                       \
  } while (0)

#define BARx() __builtin_amdgcn_s_barrier()
#define WLGx() asm volatile("s_waitcnt lgkmcnt(0)" ::: "memory")
#define WVM8() asm volatile("s_waitcnt vmcnt(8)" ::: "memory")
#define PR1() __builtin_amdgcn_s_setprio(1)
#define PR0() __builtin_amdgcn_s_setprio(0)

  // prologue: A(t0),B(t0) then A(t1),B(t1) = 16 loads/thread.
  STA(0, 0, 0);
  STA(0, 1, 0);
  STB(0, 0, 0);
  STB(0, 1, 0);
  STA(1, 0, 1);
  STA(1, 1, 1);
  STB(1, 0, 1);
  STB(1, 1, 1);
  WVM8();
  BARx();

  // K-step t: stage A(t+2) at P1-P2, B(t+2) at P3-P4; vmcnt(8) at P4
  // retires everything staged before this K-step (tile t+1 complete).
  int a = 0;
  for (int t = 0; t < NT; ++t) {
    const int b = t & 1;
    int a2 = a + 2;
    if (a2 >= 3) a2 -= 3;
    const int kt2 = (t + 2 < NT) ? t + 2 : NT - 1;  // clamped tail restage
    // P1 (12 ds_reads)
    DSBq(b);
    DSAq(a, 0);
    STA(a2, 0, kt2);
    BARx();
    WLGx();
    PR1();
    MMq(0);
    PR0();
    BARx();
    // P2
    DSAq(a, 1);
    STA(a2, 1, kt2);
    BARx();
    WLGx();
    PR1();
    MMq(1);
    PR0();
    BARx();
    // P3 (Bs[b] stage-safe: B(t) regs read at P1)
    DSAq(a, 2);
    STB(b, 0, kt2);
    BARx();
    WLGx();
    PR1();
    MMq(2);
    PR0();
    BARx();
    // P4
    DSAq(a, 3);
    STB(b, 1, kt2);
    BARx();
    WLGx();
    PR1();
    MMq(3);
    PR0();
    WVM8();
    BARx();
    ++a;
    if (a == 3) a = 0;
  }
  asm volatile("s_waitcnt vmcnt(0)" ::: "memory");

  // epilogue: D row = quad*4+r, col = l16 within each 16x16 tile
  const long long orow0 = (long long)bm * 256 + wr * 128 + quad * 4;
  const int ocol0 = bn * 256 + wc * 64 + l16;
  if (out_bf16) {
    unsigned short* Cp = (unsigned short*)C + (long long)bz * sC;
#pragma unroll
    for (int mi = 0; mi < 8; ++mi)
#pragma unroll
      for (int ni = 0; ni < 4; ++ni) {
        const int col = ocol0 + ni * 16;
        const float bv = bias ? bias[col] : 0.f;
#pragma unroll
        for (int r = 0; r < 4; ++r) {
          const float o = acc[mi][ni][r] * alpha + bv;
          Cp[(orow0 + mi * 16 + r) * N + col] = f32_to_bf16(o);
        }
      }
  } else {
    float* Cp = (float*)C + (long long)bz * sC;
#pragma unroll
    for (int mi = 0; mi < 8; ++mi)
#pragma unroll
      for (int ni = 0; ni < 4; ++ni) {
        const int col = ocol0 + ni * 16;
        const float bv = bias ? bias[col] : 0.f;
#pragma unroll
        for (int r = 0; r < 4; ++r) {
          const float o = acc[mi][ni][r] * alpha + bv;
          Cp[(orow0 + mi * 16 + r) * N + col] = o;
        }
      }
  }
#undef STA
#undef STB
#undef DSAq
#undef DSBq
#undef MMq
#undef BARx
#undef WLGx
#undef WVM8
#undef PR1
#undef PR0
}

// ------------------------------------------- gemm (B^T form), 128x256 3-buf
// C[b][M][N] = alpha * A[b][M][K] * B[b][N][K]^T + bias
//   bias_row==0: bias[col]; bias_row==1: bias[row].
// Requires M%128==0, N%256==0, K%64==0, K>=128, blocks%8==0.
__global__ __launch_bounds__(512, 2) void gemm_bt128x256(
    const unsigned short* __restrict__ A, const unsigned short* __restrict__ B,
    void* __restrict__ C, const float* __restrict__ bias,
    int M, int N, int K, float alpha, int out_bf16, int bias_row,
    int lda, int ldb, long long sA, long long sB, long long sC) {
  __shared__ unsigned short As[3][128][64];  // 48KB  [buf][row][k]
  __shared__ unsigned short Bs[3][256][64];  // 96KB

  // T1 XCD swizzle (bijective: all call-site grids are multiples of 8)
  const int hw = blockIdx.x + gridDim.x * (blockIdx.y + gridDim.y * blockIdx.z);
  const int nwg = gridDim.x * gridDim.y * gridDim.z;
  const int lg = (hw & 7) * (nwg >> 3) + (hw >> 3);
  const int bn = lg % gridDim.x;
  const int rem = lg / gridDim.x;
  const int bm = rem % gridDim.y;
  const int bz = rem / gridDim.y;

  A += (long long)bz * sA;
  B += (long long)bz * sB;

  const int tid = threadIdx.x;
  const int lane = tid & 63, wave = tid >> 6;
  const int wr = wave >> 2;             // M 64-row slice (0..1)
  const int wc = wave & 3;              // N 64-col slice (0..3)
  const int l16 = lane & 15, quad = lane >> 4;
  const int pc0 = (quad ^ (l16 & 7)) * 8;
  const int pc1 = ((4 + quad) ^ (l16 & 7)) * 8;

  const int srow = tid >> 3;
  const int lch = (tid & 7) ^ (srow & 7);
  const unsigned short* gA0 = A + (long long)(bm * 128 + srow) * lda + lch * 8;
  const unsigned short* gB0 = B + (long long)(bn * 256 + srow) * ldb + lch * 8;

  f32x4 acc[4][4] = {};
  bf16x8 af[2][2];  // 2 mi rows per phase
  bf16x8 bf[4][2];  // whole K-tile B fragments (loaded at ph0)

  const int NT = K >> 6;  // 64-wide K tiles

#define STG_A(BUF, KT)                                                      \
  do {                                                                      \
    const unsigned short* _s = gA0 + (long long)(KT) * 64;                  \
    char* _d = (char*)&As[BUF][0][0] + wave * 1024;                         \
    load_lds16(_s, _d);                                                     \
    load_lds16(_s + (long long)64 * lda, _d + 8192);                        \
  } while (0)
#define STG_B(BUF, KT, J0, JN)                                              \
  do {                                                                      \
    const unsigned short* _s = gB0 + (long long)(KT) * 64;                  \
    char* _d = (char*)&Bs[BUF][0][0] + wave * 1024;                         \
    _Pragma("unroll") for (int _j = (J0); _j < (JN); ++_j)                  \
        load_lds16(_s + (long long)(_j * 64) * ldb, _d + _j * 8192);        \
  } while (0)

#define DSA(BUF, P)                                                         \
  do {                                                                      \
    _Pragma("unroll") for (int m2 = 0; m2 < 2; ++m2) {                      \
      const unsigned short* _r =                                            \
          &As[BUF][wr * 64 + ((P) * 2 + m2) * 16 + l16][0];                 \
      af[m2][0] = *(const bf16x8*)(_r + pc0);                               \
      af[m2][1] = *(const bf16x8*)(_r + pc1);                               \
    }                                                                       \
  } while (0)

#define DSB(BUF)                                                            \
  do {                                                                      \
    _Pragma("unroll") for (int ni = 0; ni < 4; ++ni) {                      \
      const unsigned short* _r = &Bs[BUF][wc * 64 + ni * 16 + l16][0];      \
      bf[ni][0] = *(const bf16x8*)(_r + pc0);                               \
      bf[ni][1] = *(const bf16x8*)(_r + pc1);                               \
    }                                                                       \
  } while (0)

#define MM(P)                                                               \
  do {                                                                      \
    _Pragma("unroll") for (int m2 = 0; m2 < 2; ++m2)                        \
        _Pragma("unroll") for (int ni = 0; ni < 4; ++ni) {                  \
      f32x4* _a = &acc[(P) * 2 + m2][ni];                                   \
      *_a = __builtin_amdgcn_mfma_f32_16x16x32_bf16(af[m2][0], bf[ni][0],   \
                                                    *_a, 0, 0, 0);          \
      *_a = __builtin_amdgcn_mfma_f32_16x16x32_bf16(af[m2][1], bf[ni][1],   \
                                                    *_a, 0, 0, 0);          \
    }                                                                       \
  } while (0)

#define BAR() __builtin_amdgcn_s_barrier()
#define WLG() asm volatile("s_waitcnt lgkmcnt(0)" ::: "memory")
#define WVM6() asm volatile("s_waitcnt vmcnt(6)" ::: "memory")
#define P1x() __builtin_amdgcn_s_setprio(1)
#define P0x() __builtin_amdgcn_s_setprio(0)

  // prologue: tiles 0 -> buf0, 1 -> buf1 (6 loads/thread each).
  STG_A(0, 0);
  STG_B(0, 0, 0, 4);
  STG_A(1, 1);
  STG_B(1, 1, 0, 4);
  WVM6();
  BAR();

  int cur = 0;
  for (int t = 0; t < NT; ++t) {
    int b2 = cur + 2;
    if (b2 >= 3) b2 -= 3;
    const int kt = (t + 2 < NT) ? t + 2 : NT - 1;  // clamped tail restage
    // ph0
    DSB(cur);
    DSA(cur, 0);
    STG_A(b2, kt);
    STG_B(b2, kt, 0, 1);
    BAR();
    WLG();
    P1x();
    MM(0);
    P0x();
    BAR();
    // ph1
    DSA(cur, 1);
    STG_B(b2, kt, 1, 4);
    BAR();
    WLG();
    P1x();
    MM(1);
    P0x();
    WVM6();
    BAR();
    ++cur;
    if (cur == 3) cur = 0;
  }
  asm volatile("s_waitcnt vmcnt(0)" ::: "memory");

  // epilogue: D row = quad*4+r, col = l16 within each 16x16 tile
  const long long orow0 = (long long)bm * 128 + wr * 64 + quad * 4;
  const int ocol0 = bn * 256 + wc * 64 + l16;
  if (out_bf16) {
    unsigned short* Cp = (unsigned short*)C + (long long)bz * sC;
#pragma unroll
    for (int mi = 0; mi < 4; ++mi)
#pragma unroll
      for (int ni = 0; ni < 4; ++ni) {
        const int col = ocol0 + ni * 16;
        const float bcol = (bias && !bias_row) ? bias[col] : 0.f;
#pragma unroll
        for (int r = 0; r < 4; ++r) {
          const float bv =
              (bias && bias_row) ? bias[orow0 + mi * 16 + r] : bcol;
          const float o = acc[mi][ni][r] * alpha + bv;
          Cp[(orow0 + mi * 16 + r) * N + col] = f32_to_bf16(o);
        }
      }
  } else {
    float* Cp = (float*)C + (long long)bz * sC;
#pragma unroll
    for (int mi = 0; mi < 4; ++mi)
#pragma unroll
      for (int ni = 0; ni < 4; ++ni) {
        const int col = ocol0 + ni * 16;
        const float bcol = (bias && !bias_row) ? bias[col] : 0.f;
#pragma unroll
        for (int r = 0; r < 4; ++r) {
          const float bv =
              (bias && bias_row) ? bias[orow0 + mi * 16 + r] : bcol;
          const float o = acc[mi][ni][r] * alpha + bv;
          Cp[(orow0 + mi * 16 + r) * N + col] = o;
        }
      }
  }
#undef STG_A
#undef STG_B
#undef DSA
#undef DSB
#undef MM
#undef BAR
#undef WLG
#undef WVM6
#undef P1x
#undef P0x
}

// ------------------------------------------------------------- row softmax
// S: [8192][2048] fp32 -> P: [8192][2048] bf16. One block per row.
__global__ __launch_bounds__(256) void softmax_rows(
    const float* __restrict__ S, unsigned short* __restrict__ P) {
  const long long row = blockIdx.x;
  const float* s = S + row * 2048;
  const int t = threadIdx.x;
  float v[8];
  float mx = -3.4e38f;
#pragma unroll
  for (int i = 0; i < 8; i++) {
    v[i] = s[t + i * 256];
    mx = fmaxf(mx, v[i]);
  }
#pragma unroll
  for (int o = 32; o >= 1; o >>= 1) mx = fmaxf(mx, __shfl_xor(mx, o));
  __shared__ float red[4], red2[4];
  if ((t & 63) == 0) red[t >> 6] = mx;
  __syncthreads();
  mx = fmaxf(fmaxf(red[0], red[1]), fmaxf(red[2], red[3]));
  float sum = 0.f;
#pragma unroll
  for (int i = 0; i < 8; i++) {
    v[i] = __expf(v[i] - mx);
    sum += v[i];
  }
#pragma unroll
  for (int o = 32; o >= 1; o >>= 1) sum += __shfl_xor(sum, o);
  if ((t & 63) == 0) red2[t >> 6] = sum;
  __syncthreads();
  sum = red2[0] + red2[1] + red2[2] + red2[3];
  const float inv = 1.0f / sum;
  unsigned short* p = P + row * 2048;
#pragma unroll
  for (int i = 0; i < 8; i++) p[t + i * 256] = f32_to_bf16(v[i] * inv);
}

// ----------------------------------------------------------------- launcher
extern "C" void kernel_launch(void* const* d_in, const int* in_sizes, int n_in,
                              void* d_out, int out_size, void* d_ws,
                              size_t ws_size, hipStream_t stream) {
  const float* x = (const float*)d_in[0];
  const float* wq = (const float*)d_in[1];
  const float* bq = (const float*)d_in[2];
  const float* wk = (const float*)d_in[3];
  const float* bk = (const float*)d_in[4];
  const float* wv = (const float*)d_in[5];
  const float* bv = (const float*)d_in[6];
  const float* wo = (const float*)d_in[7];
  const float* bo = (const float*)d_in[8];
  float* out = (float*)d_out;
  char* ws = (char*)d_ws;
  const size_t MB = 1ull << 20;

  unsigned short* xb  = (unsigned short*)(ws + 0);        // 16MB, later O
  unsigned short* wqk = (unsigned short*)(ws + 16 * MB);  // 4MB [2048][1024]
  unsigned short* wvb = (unsigned short*)(ws + 20 * MB);  // 2MB
  unsigned short* wob = (unsigned short*)(ws + 22 * MB);  // 2MB
  unsigned short* QKm = (unsigned short*)(ws + 24 * MB);  // 32MB [8192][2048]
  unsigned short* VT  = (unsigned short*)(ws + 56 * MB);  // 16MB [1024][8192]
  float*          S   = (float*)(ws + 72 * MB);           // 64MB
  float*          bqk = (float*)(ws + 72 * MB);           // 8KB, dies at S
  unsigned short* P   = QKm;                              // 32MB over QK
  unsigned short* O   = xb;                               // 16MB over x_bf16

  // 1) fused prep: all casts + bias concat (one launch)
  prep<<<dim3(12290), dim3(256), 0, stream>>>(
      (const float4*)x, (const float4*)wq, (const float4*)wk,
      (const float4*)wv, (const float4*)wo, (const float4*)bq,
      (const float4*)bk, (ushort4*)xb, (ushort4*)wqk, (ushort4*)wvb,
      (ushort4*)wob, (float4*)bqk);

  // 2) fused QK projection: [8192,2048] = x_bf16 @ [wq;wk]^T + bqk
  //    256dp engine, grid 8x32 = 256 blocks = 1 full round
  gemm_bt256dp<<<dim3(8, 32, 1), dim3(512), 0, stream>>>(
      xb, wqk, QKm, bqk, 8192, 2048, 1024, 1.f, 1, 1024, 1024, 0, 0, 0);

  // 3) VT[d][s] = sum_k w_v[d,k] x[s,k] + bv[d]  (per-ROW bias)
  //    128x256 engine, grid 32x8 = 256 blocks
  gemm_bt128x256<<<dim3(32, 8, 1), dim3(512), 0, stream>>>(
      wvb, xb, VT, bv, 1024, 8192, 1024, 1.f, 1, 1, 1024, 1024, 0, 0, 0);

  // 4) S = Q K^T / 32, fp32, batched over 4 (Q,K are column slices of QKm)
  //    256dp engine, grid 8x8x4 = 256 blocks = 1 full round
  gemm_bt256dp<<<dim3(8, 8, 4), dim3(512), 0, stream>>>(
      QKm, QKm + 1024, S, nullptr, 2048, 2048, 1024, 0.03125f, 0, 2048, 2048,
      2048ll * 2048, 2048ll * 2048, 2048ll * 2048);

  // 5) P = softmax rows of S (bf16), over dead QK region
  softmax_rows<<<dim3(8192), dim3(256), 0, stream>>>(S, P);

  // 6) O = P @ V: B = VT (batch b at column offset b*2048, ldb=8192)
  //    128x256 engine, grid 4x16x4 = 256 blocks
  gemm_bt128x256<<<dim3(4, 16, 4), dim3(512), 0, stream>>>(
      P, VT, O, nullptr, 2048, 1024, 2048, 1.f, 1, 0, 2048, 8192,
      2048ll * 2048, 2048ll, 2048ll * 1024);

  // 7) out = O @ Wo^T + bo, fp32 — 128x256 engine, grid 4x64 = 256 blocks
  gemm_bt128x256<<<dim3(4, 64, 1), dim3(512), 0, stream>>>(
      O, wob, out, bo, 8192, 1024, 1024, 1.f, 0, 0, 1024, 1024, 0, 0, 0);
}